// Round 1
// baseline (190.921 us; speedup 1.0000x reference)
//
#include <hip/hip_runtime.h>

// top_k_gating: per row of 64 fp32 weights, keep top-8 (ties -> lower index,
// matching jax.lax.top_k), zero the rest, L1-renormalize with eps clamp.
//
// One thread per row. 64 values held in VGPRs via unrolled float4 loads.
// Branchless sorted top-8 (ascending t[0..7], t[0] = 8th largest):
//   t[0] = max(t[0], x); then one bubble pass of 7 compare-swaps.
// Memory-bound design: 256B read + 256B write per row, fully vectorized.

constexpr int E = 64;
constexpr int K = 8;
constexpr float L1_EPS = 1e-12f;

__global__ __launch_bounds__(256) void topk_gate_kernel(
    const float* __restrict__ w, float* __restrict__ out, int B)
{
    const int row = blockIdx.x * blockDim.x + threadIdx.x;
    if (row >= B) return;

    const float4* __restrict__ src =
        reinterpret_cast<const float4*>(w + (size_t)row * E);

    float v[E];
    #pragma unroll
    for (int i = 0; i < E / 4; ++i) {
        const float4 t4 = src[i];
        v[4 * i + 0] = t4.x;
        v[4 * i + 1] = t4.y;
        v[4 * i + 2] = t4.z;
        v[4 * i + 3] = t4.w;
    }

    // Maintain ascending top-8; t[0] is the running 8th-largest.
    float t[K];
    #pragma unroll
    for (int j = 0; j < K; ++j) t[j] = -__builtin_inff();

    #pragma unroll
    for (int i = 0; i < E; ++i) {
        const float x = v[i];
        t[0] = fmaxf(t[0], x);  // replace current min of top-8 if larger
        #pragma unroll
        for (int j = 0; j < K - 1; ++j) {  // single bubble pass restores order
            const float lo = fminf(t[j], t[j + 1]);
            const float hi = fmaxf(t[j], t[j + 1]);
            t[j] = lo;
            t[j + 1] = hi;
        }
    }
    const float thr = t[0];  // value of the 8th largest

    // Strictly-greater count; equals admitted in index order (top_k tie-break).
    int cgt = 0;
    #pragma unroll
    for (int i = 0; i < E; ++i) cgt += (v[i] > thr) ? 1 : 0;
    const int budget = K - cgt;  // how many ==thr entries to keep

    unsigned long long mask = 0ull;
    float l1 = 0.0f;
    int eqseen = 0;
    #pragma unroll
    for (int i = 0; i < E; ++i) {
        const float x = v[i];
        const bool gt = x > thr;
        const bool eq = x == thr;
        const bool take = gt || (eq && (eqseen < budget));
        eqseen += eq ? 1 : 0;
        mask |= (unsigned long long)(take ? 1ull : 0ull) << i;
        l1 += take ? fabsf(x) : 0.0f;
    }

    const float scale = 1.0f / fmaxf(l1, L1_EPS);

    float4* __restrict__ dst = reinterpret_cast<float4*>(out + (size_t)row * E);
    #pragma unroll
    for (int i = 0; i < E / 4; ++i) {
        float4 o;
        o.x = ((mask >> (4 * i + 0)) & 1ull) ? v[4 * i + 0] * scale : 0.0f;
        o.y = ((mask >> (4 * i + 1)) & 1ull) ? v[4 * i + 1] * scale : 0.0f;
        o.z = ((mask >> (4 * i + 2)) & 1ull) ? v[4 * i + 2] * scale : 0.0f;
        o.w = ((mask >> (4 * i + 3)) & 1ull) ? v[4 * i + 3] * scale : 0.0f;
        dst[i] = o;
    }
}

extern "C" void kernel_launch(void* const* d_in, const int* in_sizes, int n_in,
                              void* d_out, int out_size, void* d_ws, size_t ws_size,
                              hipStream_t stream) {
    const float* w = (const float*)d_in[0];
    // d_in[1] is k (always 8 in this harness; kernel is compile-time K=8).
    float* out = (float*)d_out;
    const int B = in_sizes[0] / E;

    const int block = 256;
    const int grid = (B + block - 1) / block;
    topk_gate_kernel<<<grid, block, 0, stream>>>(w, out, B);
}

// Round 2
// 129.560 us; speedup vs baseline: 1.4736x; 1.4736x over previous
//
#include <hip/hip_runtime.h>

// top_k_gating, wave-cooperative version.
//
// Each wave processes 4 rows per iteration: lane l holds the float4 at byte
// offset l*16 within the wave's contiguous 1KB span -> loads AND stores are
// perfectly coalesced (fixes round-1's 1.66x write amplification: stores were
// 16B pieces at stride 256B -> partial-line HBM writes).
//
// 16 lanes per row (group g = lane&15), 4 values per lane. The 8th-largest
// value (threshold) is found with an in-register bitonic ladder:
//   sort-4 desc per lane -> merge with lane^1 (sorted-8) -> top-8 merge with
//   lane^2 -> top-8 merge with lane^4 -> final merge with lane^8, take min.
// Ties at the threshold are admitted in column order (lower index first,
// matching jax.lax.top_k) via a 16-lane prefix sum of equal-counts.

constexpr int E = 64;
constexpr float L1_EPS = 1e-12f;
constexpr int WAVES_PER_BLOCK = 4;   // 256 threads
constexpr int ITER = 8;              // row-quads per wave

// compare-exchange, descending (index i keeps the max)
#define CE(x, y) { const float _hi = fmaxf(x, y); const float _lo = fminf(x, y); (x) = _hi; (y) = _lo; }

__global__ __launch_bounds__(256) void topk_gate_coop(
    const float* __restrict__ w, float* __restrict__ out, int B)
{
    const int lane = threadIdx.x & 63;
    const int wv   = threadIdx.x >> 6;
    const int gw   = blockIdx.x * WAVES_PER_BLOCK + wv;
    const int g    = lane & 15;      // position within the 16-lane row group

    for (int t = 0; t < ITER; ++t) {
        const int rowBlock = (gw * ITER + t) * 4;   // first of 4 rows
        if (rowBlock >= B) return;                   // wave-uniform

        // ---- coalesced load: lane l takes float4 #l of the 1KB span ----
        const float4 v4 =
            reinterpret_cast<const float4*>(w)[(size_t)rowBlock * 16 + lane];
        const float v0 = v4.x, v1 = v4.y, v2 = v4.z, v3 = v4.w;

        // ---- step 0: sort my 4 values descending ----
        float a0 = v0, a1 = v1, a2 = v2, a3 = v3;
        CE(a0, a1) CE(a2, a3) CE(a0, a2) CE(a1, a3) CE(a1, a2)

        // ---- step 1 (xor 1): merge my sorted-4 with partner's -> sorted-8 ----
        float s[8];
        s[0] = a0; s[1] = a1; s[2] = a2; s[3] = a3;
        s[4] = __shfl_xor(a3, 1);   // partner reversed -> bitonic sequence
        s[5] = __shfl_xor(a2, 1);
        s[6] = __shfl_xor(a1, 1);
        s[7] = __shfl_xor(a0, 1);
        CE(s[0], s[4]) CE(s[1], s[5]) CE(s[2], s[6]) CE(s[3], s[7])
        CE(s[0], s[2]) CE(s[1], s[3]) CE(s[4], s[6]) CE(s[5], s[7])
        CE(s[0], s[1]) CE(s[2], s[3]) CE(s[4], s[5]) CE(s[6], s[7])

        // ---- steps 2,3 (xor 2, xor 4): keep top-8 of my-8 + partner-8 ----
        #pragma unroll
        for (int m = 2; m <= 4; m <<= 1) {
            float p[8];
            #pragma unroll
            for (int i = 0; i < 8; ++i) p[i] = __shfl_xor(s[i], m);
            float c[8];
            #pragma unroll
            for (int i = 0; i < 8; ++i) c[i] = fmaxf(s[i], p[7 - i]);
            // c holds the top-8 multiset as a bitonic sequence; re-sort desc
            #pragma unroll
            for (int i = 0; i < 8; ++i) s[i] = c[i];
            CE(s[0], s[4]) CE(s[1], s[5]) CE(s[2], s[6]) CE(s[3], s[7])
            CE(s[0], s[2]) CE(s[1], s[3]) CE(s[4], s[6]) CE(s[5], s[7])
            CE(s[0], s[1]) CE(s[2], s[3]) CE(s[4], s[5]) CE(s[6], s[7])
        }

        // ---- step 4 (xor 8): threshold = min of merged top-8 ----
        float p[8];
        #pragma unroll
        for (int i = 0; i < 8; ++i) p[i] = __shfl_xor(s[i], 8);
        float c[8];
        #pragma unroll
        for (int i = 0; i < 8; ++i) c[i] = fmaxf(s[i], p[7 - i]);
        float thr = fminf(fminf(fminf(c[0], c[1]), fminf(c[2], c[3])),
                          fminf(fminf(c[4], c[5]), fminf(c[6], c[7])));

        // ---- tie-aware selection (lower column index wins among equals) ----
        const int lgt = (v0 > thr) + (v1 > thr) + (v2 > thr) + (v3 > thr);
        const int leq = (v0 == thr) + (v1 == thr) + (v2 == thr) + (v3 == thr);

        int cgt = lgt;
        cgt += __shfl_xor(cgt, 1);
        cgt += __shfl_xor(cgt, 2);
        cgt += __shfl_xor(cgt, 4);
        cgt += __shfl_xor(cgt, 8);
        const int budget = 8 - cgt;   // how many ==thr entries survive

        // exclusive prefix of equal-counts across the 16-lane group
        int pre = leq;
        #pragma unroll
        for (int sdt = 1; sdt < 16; sdt <<= 1) {
            const int u = __shfl_up(pre, sdt);
            if (g >= sdt) pre += u;
        }
        int eqb = pre - leq;          // equals in columns before my chunk

        const bool e0 = (v0 == thr), e1 = (v1 == thr), e2 = (v2 == thr), e3 = (v3 == thr);
        const bool take0 = (v0 > thr) || (e0 && (eqb < budget)); eqb += e0 ? 1 : 0;
        const bool take1 = (v1 > thr) || (e1 && (eqb < budget)); eqb += e1 ? 1 : 0;
        const bool take2 = (v2 > thr) || (e2 && (eqb < budget)); eqb += e2 ? 1 : 0;
        const bool take3 = (v3 > thr) || (e3 && (eqb < budget));

        // ---- L1 norm of kept values (group reduce) ----
        float l1 = (take0 ? fabsf(v0) : 0.0f) + (take1 ? fabsf(v1) : 0.0f) +
                   (take2 ? fabsf(v2) : 0.0f) + (take3 ? fabsf(v3) : 0.0f);
        l1 += __shfl_xor(l1, 1);
        l1 += __shfl_xor(l1, 2);
        l1 += __shfl_xor(l1, 4);
        l1 += __shfl_xor(l1, 8);
        const float scale = 1.0f / fmaxf(l1, L1_EPS);

        // ---- coalesced store: same float4 slot we loaded ----
        float4 o;
        o.x = take0 ? v0 * scale : 0.0f;
        o.y = take1 ? v1 * scale : 0.0f;
        o.z = take2 ? v2 * scale : 0.0f;
        o.w = take3 ? v3 * scale : 0.0f;
        reinterpret_cast<float4*>(out)[(size_t)rowBlock * 16 + lane] = o;
    }
}

extern "C" void kernel_launch(void* const* d_in, const int* in_sizes, int n_in,
                              void* d_out, int out_size, void* d_ws, size_t ws_size,
                              hipStream_t stream) {
    const float* w = (const float*)d_in[0];
    // d_in[1] is k (always 8 here; kernel is compile-time K=8).
    float* out = (float*)d_out;
    const int B = in_sizes[0] / E;

    const int rows_per_block = WAVES_PER_BLOCK * ITER * 4;   // 128
    const int grid = (B + rows_per_block - 1) / rows_per_block;
    topk_gate_coop<<<grid, 256, 0, stream>>>(w, out, B);
}

// Round 4
// 110.595 us; speedup vs baseline: 1.7263x; 1.1715x over previous
//
#include <hip/hip_runtime.h>

// top_k_gating, wave-cooperative + DPP version.
//
// Round-2 lesson: __shfl_* lowers to ds_bpermute (addr VALU + DS op + lgkm
// wait) -> ~515 wave-inst per 4-row iter, VALUBusy 73%, VALU-bound at 130us.
// Fix: every cross-lane exchange here fits a DPP16 pattern (1 VALU op, no DS):
//   xor1 = quad_perm[1,0,3,2], xor2 = quad_perm[2,3,0,1]
//   lane^7 = row_half_mirror, lane^8 = row_ror:8
// After the xor1/xor2 levels all lanes of a quad hold the same top-8 multiset,
// so the last two tournament levels may pair quads via ^7 and octets via ^8
// (xor4 is not a DPP pattern, but any quad<->quad pairing works).
// Tie-break (lower expert index among ==threshold, matching jax.lax.top_k) is
// exact: common case proven by total_eq==budget -> take = (v>=thr); rare case
// behind a wave-uniform __any() does a DPP row_shr prefix scan.
// Output stored nontemporally so 268MB of never-re-read writes don't evict
// the (nearly L3-resident) input.
//
// Round-3 fix: __builtin_nontemporal_store rejects HIP_vector_type<float,4>;
// use clang ext_vector float4 instead.

constexpr int E = 64;
constexpr float L1_EPS = 1e-12f;
constexpr int WAVES_PER_BLOCK = 4;   // 256 threads
constexpr int ITER = 8;              // row-quads per wave

typedef float f32x4 __attribute__((ext_vector_type(4)));

#define DPP_QUAD_XOR1 0xB1   // quad_perm [1,0,3,2]
#define DPP_QUAD_XOR2 0x4E   // quad_perm [2,3,0,1]
#define DPP_HALF_MIR  0x141  // row_half_mirror: lane ^ 7 (within 16)
#define DPP_ROR8      0x128  // row_ror:8: lane ^ 8 (within 16)
#define DPP_SHR1      0x111
#define DPP_SHR2      0x112
#define DPP_SHR4      0x114
#define DPP_SHR8      0x118

template <int CTRL>
__device__ __forceinline__ float dppf(float x) {
    return __int_as_float(__builtin_amdgcn_update_dpp(
        0, __float_as_int(x), CTRL, 0xF, 0xF, true));
}
template <int CTRL>
__device__ __forceinline__ int dppi(int x) {
    return __builtin_amdgcn_update_dpp(0, x, CTRL, 0xF, 0xF, true);
}

// compare-exchange, descending (first arg keeps the max)
#define CE(x, y) { const float _hi = fmaxf(x, y); const float _lo = fminf(x, y); (x) = _hi; (y) = _lo; }

// bitonic -> descending sort of 8 (12 CE)
#define SORT8(s) \
    CE(s[0], s[4]) CE(s[1], s[5]) CE(s[2], s[6]) CE(s[3], s[7]) \
    CE(s[0], s[2]) CE(s[1], s[3]) CE(s[4], s[6]) CE(s[5], s[7]) \
    CE(s[0], s[1]) CE(s[2], s[3]) CE(s[4], s[5]) CE(s[6], s[7])

// merge my sorted-8 (desc) with DPP-partner's: keep top-8, re-sort desc.
template <int CTRL>
__device__ __forceinline__ void merge8(float s[8]) {
    float c[8];
    #pragma unroll
    for (int i = 0; i < 8; ++i) c[i] = fmaxf(s[i], dppf<CTRL>(s[7 - i]));
    #pragma unroll
    for (int i = 0; i < 8; ++i) s[i] = c[i];
    SORT8(s)
}

__global__ __launch_bounds__(256) void topk_gate_dpp(
    const float* __restrict__ w, float* __restrict__ out, int B)
{
    const int lane = threadIdx.x & 63;
    const int wv   = threadIdx.x >> 6;
    const int gw   = blockIdx.x * WAVES_PER_BLOCK + wv;

    for (int t = 0; t < ITER; ++t) {
        const int rowBlock = (gw * ITER + t) * 4;    // first of 4 rows
        if (rowBlock >= B) return;                   // wave-uniform

        // coalesced: lane l owns float4 #l of the wave's 1KB span
        // (lane g=l&15 holds experts 4g..4g+3 of row rowBlock + l/16)
        const f32x4 v4 = __builtin_nontemporal_load(
            reinterpret_cast<const f32x4*>(w) + (size_t)rowBlock * 16 + lane);
        const float v0 = v4.x, v1 = v4.y, v2 = v4.z, v3 = v4.w;

        // sort my 4 descending (5 CE)
        float a0 = v0, a1 = v1, a2 = v2, a3 = v3;
        CE(a0, a1) CE(a2, a3) CE(a0, a2) CE(a1, a3) CE(a1, a2)

        // level 1 (^1): union with partner's 4 (reversed) -> bitonic -> sort-8
        float s[8];
        s[0] = a0; s[1] = a1; s[2] = a2; s[3] = a3;
        s[4] = dppf<DPP_QUAD_XOR1>(a3);
        s[5] = dppf<DPP_QUAD_XOR1>(a2);
        s[6] = dppf<DPP_QUAD_XOR1>(a1);
        s[7] = dppf<DPP_QUAD_XOR1>(a0);
        SORT8(s)

        // levels 2..4: keep top-8 across quads (^2), quad-pairs (^7), octets (^8)
        merge8<DPP_QUAD_XOR2>(s);
        merge8<DPP_HALF_MIR>(s);
        merge8<DPP_ROR8>(s);

        const float thr = s[7];   // 8th largest of the row (all 16 lanes agree)

        // strictly-greater count: all >thr values live in s[0..6]
        int cgt = 0;
        #pragma unroll
        for (int i = 0; i < 7; ++i) cgt += (s[i] > thr) ? 1 : 0;
        const int budget = 8 - cgt;           // slots for ==thr values

        const bool e0 = (v0 == thr), e1 = (v1 == thr),
                   e2 = (v2 == thr), e3 = (v3 == thr);
        int total_eq = (e0 ? 1 : 0) + (e1 ? 1 : 0) + (e2 ? 1 : 0) + (e3 ? 1 : 0);
        const int leq = total_eq;
        total_eq += dppi<DPP_QUAD_XOR1>(total_eq);
        total_eq += dppi<DPP_QUAD_XOR2>(total_eq);
        total_eq += dppi<DPP_HALF_MIR>(total_eq);
        total_eq += dppi<DPP_ROR8>(total_eq);

        bool take0, take1, take2, take3;
        if (__any(total_eq > budget)) {
            // rare: more equals than slots -> admit in expert-index order
            int incl = leq;
            incl += dppi<DPP_SHR1>(incl);
            incl += dppi<DPP_SHR2>(incl);
            incl += dppi<DPP_SHR4>(incl);
            incl += dppi<DPP_SHR8>(incl);
            int eqb = incl - leq;             // equals in lower expert indices
            take0 = (v0 > thr) || (e0 && eqb < budget); eqb += e0 ? 1 : 0;
            take1 = (v1 > thr) || (e1 && eqb < budget); eqb += e1 ? 1 : 0;
            take2 = (v2 > thr) || (e2 && eqb < budget); eqb += e2 ? 1 : 0;
            take3 = (v3 > thr) || (e3 && eqb < budget);
        } else {
            // total_eq == budget exactly -> every equal survives
            take0 = v0 >= thr; take1 = v1 >= thr;
            take2 = v2 >= thr; take3 = v3 >= thr;
        }

        // L1 of kept values, reduced across the 16-lane group via DPP butterfly
        float l1 = (take0 ? fabsf(v0) : 0.0f) + (take1 ? fabsf(v1) : 0.0f) +
                   (take2 ? fabsf(v2) : 0.0f) + (take3 ? fabsf(v3) : 0.0f);
        l1 += dppf<DPP_QUAD_XOR1>(l1);
        l1 += dppf<DPP_QUAD_XOR2>(l1);
        l1 += dppf<DPP_HALF_MIR>(l1);
        l1 += dppf<DPP_ROR8>(l1);

        const float scale = __builtin_amdgcn_rcpf(fmaxf(l1, L1_EPS));

        f32x4 o;
        o.x = take0 ? v0 * scale : 0.0f;
        o.y = take1 ? v1 * scale : 0.0f;
        o.z = take2 ? v2 * scale : 0.0f;
        o.w = take3 ? v3 * scale : 0.0f;
        __builtin_nontemporal_store(
            o, reinterpret_cast<f32x4*>(out) + (size_t)rowBlock * 16 + lane);
    }
}

extern "C" void kernel_launch(void* const* d_in, const int* in_sizes, int n_in,
                              void* d_out, int out_size, void* d_ws, size_t ws_size,
                              hipStream_t stream) {
    const float* w = (const float*)d_in[0];
    // d_in[1] is k (always 8 here; kernel is compile-time K=8).
    float* out = (float*)d_out;
    const int B = in_sizes[0] / E;

    const int rows_per_block = WAVES_PER_BLOCK * ITER * 4;   // 128
    const int grid = (B + rows_per_block - 1) / rows_per_block;
    topk_gate_dpp<<<grid, 256, 0, stream>>>(w, out, B);
}

// Round 5
// 108.045 us; speedup vs baseline: 1.7670x; 1.0236x over previous
//
#include <hip/hip_runtime.h>

// top_k_gating, wave-cooperative + DPP version, round 5.
//
// Memory strategy: input is exactly 256 MiB == L3 capacity. Round-2 counters
// showed FETCH=134MB (half L3-resident across replays) with no hints. So:
//   - input: PLAIN cached load (round 4's nontemporal load discarded L3
//     residency -- reverted)
//   - output: nontemporal store (write-once data must not evict the input)
//
// Cross-lane: all exchanges are DPP16 patterns (1 VALU op, no DS path):
//   xor1 = quad_perm[1,0,3,2], xor2 = quad_perm[2,3,0,1]
//   lane^7 = row_half_mirror, lane^8 = row_ror:8
// 16 lanes per row, 4 values per lane; sorted-4 -> sorted-8 -> 3 top-8 merges
// -> thr = 8th largest. Tie-break (lower expert index among ==thr, matching
// jax.lax.top_k) exact; rare over-budget case behind wave-uniform __any().

constexpr int E = 64;
constexpr float L1_EPS = 1e-12f;
constexpr int WAVES_PER_BLOCK = 4;   // 256 threads
constexpr int ITER = 8;              // row-quads per wave

typedef float f32x4 __attribute__((ext_vector_type(4)));

#define DPP_QUAD_XOR1 0xB1   // quad_perm [1,0,3,2]
#define DPP_QUAD_XOR2 0x4E   // quad_perm [2,3,0,1]
#define DPP_HALF_MIR  0x141  // row_half_mirror: lane ^ 7 (within 16)
#define DPP_ROR8      0x128  // row_ror:8: lane ^ 8 (within 16)
#define DPP_SHR1      0x111
#define DPP_SHR2      0x112
#define DPP_SHR4      0x114
#define DPP_SHR8      0x118

template <int CTRL>
__device__ __forceinline__ float dppf(float x) {
    return __int_as_float(__builtin_amdgcn_update_dpp(
        0, __float_as_int(x), CTRL, 0xF, 0xF, true));
}
template <int CTRL>
__device__ __forceinline__ int dppi(int x) {
    return __builtin_amdgcn_update_dpp(0, x, CTRL, 0xF, 0xF, true);
}

// compare-exchange, descending (first arg keeps the max)
#define CE(x, y) { const float _hi = fmaxf(x, y); const float _lo = fminf(x, y); (x) = _hi; (y) = _lo; }

// bitonic -> descending sort of 8 (12 CE)
#define SORT8(s) \
    CE(s[0], s[4]) CE(s[1], s[5]) CE(s[2], s[6]) CE(s[3], s[7]) \
    CE(s[0], s[2]) CE(s[1], s[3]) CE(s[4], s[6]) CE(s[5], s[7]) \
    CE(s[0], s[1]) CE(s[2], s[3]) CE(s[4], s[5]) CE(s[6], s[7])

// merge my sorted-8 (desc) with DPP-partner's: keep top-8, re-sort desc.
template <int CTRL>
__device__ __forceinline__ void merge8(float s[8]) {
    float c[8];
    #pragma unroll
    for (int i = 0; i < 8; ++i) c[i] = fmaxf(s[i], dppf<CTRL>(s[7 - i]));
    #pragma unroll
    for (int i = 0; i < 8; ++i) s[i] = c[i];
    SORT8(s)
}

__global__ __launch_bounds__(256) void topk_gate_dpp(
    const float* __restrict__ w, float* __restrict__ out, int B)
{
    const int lane = threadIdx.x & 63;
    const int wv   = threadIdx.x >> 6;
    const int gw   = blockIdx.x * WAVES_PER_BLOCK + wv;

    for (int t = 0; t < ITER; ++t) {
        const int rowBlock = (gw * ITER + t) * 4;    // first of 4 rows
        if (rowBlock >= B) return;                   // wave-uniform

        // coalesced cached load: lane l owns float4 #l of the wave's 1KB span
        // (lane g=l&15 holds experts 4g..4g+3 of row rowBlock + l/16)
        const f32x4 v4 =
            reinterpret_cast<const f32x4*>(w)[(size_t)rowBlock * 16 + lane];
        const float v0 = v4.x, v1 = v4.y, v2 = v4.z, v3 = v4.w;

        // sort my 4 descending (5 CE)
        float a0 = v0, a1 = v1, a2 = v2, a3 = v3;
        CE(a0, a1) CE(a2, a3) CE(a0, a2) CE(a1, a3) CE(a1, a2)

        // level 1 (^1): union with partner's 4 (reversed) -> bitonic -> sort-8
        float s[8];
        s[0] = a0; s[1] = a1; s[2] = a2; s[3] = a3;
        s[4] = dppf<DPP_QUAD_XOR1>(a3);
        s[5] = dppf<DPP_QUAD_XOR1>(a2);
        s[6] = dppf<DPP_QUAD_XOR1>(a1);
        s[7] = dppf<DPP_QUAD_XOR1>(a0);
        SORT8(s)

        // levels 2..4: keep top-8 across quads (^2), quad-pairs (^7), octets (^8)
        merge8<DPP_QUAD_XOR2>(s);
        merge8<DPP_HALF_MIR>(s);
        merge8<DPP_ROR8>(s);

        const float thr = s[7];   // 8th largest of the row (all 16 lanes agree)

        // strictly-greater count: all >thr values live in s[0..6]
        int cgt = 0;
        #pragma unroll
        for (int i = 0; i < 7; ++i) cgt += (s[i] > thr) ? 1 : 0;
        const int budget = 8 - cgt;           // slots for ==thr values

        const bool e0 = (v0 == thr), e1 = (v1 == thr),
                   e2 = (v2 == thr), e3 = (v3 == thr);
        int total_eq = (e0 ? 1 : 0) + (e1 ? 1 : 0) + (e2 ? 1 : 0) + (e3 ? 1 : 0);
        const int leq = total_eq;
        total_eq += dppi<DPP_QUAD_XOR1>(total_eq);
        total_eq += dppi<DPP_QUAD_XOR2>(total_eq);
        total_eq += dppi<DPP_HALF_MIR>(total_eq);
        total_eq += dppi<DPP_ROR8>(total_eq);

        bool take0, take1, take2, take3;
        if (__any(total_eq > budget)) {
            // rare: more equals than slots -> admit in expert-index order
            int incl = leq;
            incl += dppi<DPP_SHR1>(incl);
            incl += dppi<DPP_SHR2>(incl);
            incl += dppi<DPP_SHR4>(incl);
            incl += dppi<DPP_SHR8>(incl);
            int eqb = incl - leq;             // equals in lower expert indices
            take0 = (v0 > thr) || (e0 && eqb < budget); eqb += e0 ? 1 : 0;
            take1 = (v1 > thr) || (e1 && eqb < budget); eqb += e1 ? 1 : 0;
            take2 = (v2 > thr) || (e2 && eqb < budget); eqb += e2 ? 1 : 0;
            take3 = (v3 > thr) || (e3 && eqb < budget);
        } else {
            // total_eq == budget exactly -> every equal survives
            take0 = v0 >= thr; take1 = v1 >= thr;
            take2 = v2 >= thr; take3 = v3 >= thr;
        }

        // L1 of kept values, reduced across the 16-lane group via DPP butterfly
        float l1 = (take0 ? fabsf(v0) : 0.0f) + (take1 ? fabsf(v1) : 0.0f) +
                   (take2 ? fabsf(v2) : 0.0f) + (take3 ? fabsf(v3) : 0.0f);
        l1 += dppf<DPP_QUAD_XOR1>(l1);
        l1 += dppf<DPP_QUAD_XOR2>(l1);
        l1 += dppf<DPP_HALF_MIR>(l1);
        l1 += dppf<DPP_ROR8>(l1);

        const float scale = __builtin_amdgcn_rcpf(fmaxf(l1, L1_EPS));

        f32x4 o;
        o.x = take0 ? v0 * scale : 0.0f;
        o.y = take1 ? v1 * scale : 0.0f;
        o.z = take2 ? v2 * scale : 0.0f;
        o.w = take3 ? v3 * scale : 0.0f;
        __builtin_nontemporal_store(
            o, reinterpret_cast<f32x4*>(out) + (size_t)rowBlock * 16 + lane);
    }
}

extern "C" void kernel_launch(void* const* d_in, const int* in_sizes, int n_in,
                              void* d_out, int out_size, void* d_ws, size_t ws_size,
                              hipStream_t stream) {
    const float* w = (const float*)d_in[0];
    // d_in[1] is k (always 8 here; kernel is compile-time K=8).
    float* out = (float*)d_out;
    const int B = in_sizes[0] / E;

    const int rows_per_block = WAVES_PER_BLOCK * ITER * 4;   // 128
    const int grid = (B + rows_per_block - 1) / rows_per_block;
    topk_gate_dpp<<<grid, 256, 0, stream>>>(w, out, B);
}

// Round 6
// 103.599 us; speedup vs baseline: 1.8429x; 1.0429x over previous
//
#include <hip/hip_runtime.h>

// top_k_gating round 6: 8 lanes/row x 8 values/lane (was 16x4).
//
// Why: round-5 counters showed VALUBusy 65% -- selection network ~60us vs
// ~64us memory floor. With 8 rows per wave-iter the tournament amortizes 2x
// better and one merge level disappears:
//   per-lane Batcher sort-8 (19 CE) -> top8-merge ^1 -> top8-merge ^2
//   -> final mirror merge (min-tree only, no cleanup sort).
// After the final merge each lane holds the row's top-8 multiset c[]:
//   thr  = min(c)            (7 fmin)
//   cgt  = #(c > thr)        (no cross-lane reduce)
//   l1   = sum |c|           (kept multiset == top-8 multiset, ties included)
// Cross-lane exchanges are DPP16 only (quad_perm ^1, ^2; row_half_mirror
// pairs the two quads of each 8-lane group). Tie-break (lower expert index,
// matching jax.lax.top_k) exact; over-budget case is cold and uses
// __shfl_up(width=8) prefix scan.
// Memory: plain cached loads (input ~L3-resident), nontemporal stores
// (write-once output must not evict input).

constexpr int E = 64;
constexpr float L1_EPS = 1e-12f;
constexpr int WAVES_PER_BLOCK = 4;   // 256 threads
constexpr int ITER = 8;              // row-octets per wave

typedef float f32x4 __attribute__((ext_vector_type(4)));

#define DPP_QUAD_XOR1 0xB1   // quad_perm [1,0,3,2]
#define DPP_QUAD_XOR2 0x4E   // quad_perm [2,3,0,1]
#define DPP_HALF_MIR  0x141  // row_half_mirror: lane i <-> 7-i within each 8

template <int CTRL>
__device__ __forceinline__ float dppf(float x) {
    return __int_as_float(__builtin_amdgcn_update_dpp(
        0, __float_as_int(x), CTRL, 0xF, 0xF, true));
}
template <int CTRL>
__device__ __forceinline__ int dppi(int x) {
    return __builtin_amdgcn_update_dpp(0, x, CTRL, 0xF, 0xF, true);
}

// compare-exchange, descending (first arg keeps the max)
#define CE(x, y) { const float _hi = fmaxf(x, y); const float _lo = fminf(x, y); (x) = _hi; (y) = _lo; }

// Batcher odd-even sort-8, descending, 19 CE
#define SORT8_FULL(s) \
    CE(s[0], s[1]) CE(s[2], s[3]) CE(s[0], s[2]) CE(s[1], s[3]) CE(s[1], s[2]) \
    CE(s[4], s[5]) CE(s[6], s[7]) CE(s[4], s[6]) CE(s[5], s[7]) CE(s[5], s[6]) \
    CE(s[0], s[4]) CE(s[1], s[5]) CE(s[2], s[6]) CE(s[3], s[7]) \
    CE(s[2], s[4]) CE(s[3], s[5]) CE(s[1], s[2]) CE(s[3], s[4]) CE(s[5], s[6])

// bitonic cleanup (sorts any bitonic sequence desc), 12 CE
#define SORT8_BITONIC(s) \
    CE(s[0], s[4]) CE(s[1], s[5]) CE(s[2], s[6]) CE(s[3], s[7]) \
    CE(s[0], s[2]) CE(s[1], s[3]) CE(s[4], s[6]) CE(s[5], s[7]) \
    CE(s[0], s[1]) CE(s[2], s[3]) CE(s[4], s[5]) CE(s[6], s[7])

// merge my sorted-8 (desc) with DPP-partner's: keep top-8, re-sort desc
template <int CTRL>
__device__ __forceinline__ void merge8(float s[8]) {
    float c[8];
    #pragma unroll
    for (int i = 0; i < 8; ++i) c[i] = fmaxf(s[i], dppf<CTRL>(s[7 - i]));
    #pragma unroll
    for (int i = 0; i < 8; ++i) s[i] = c[i];
    SORT8_BITONIC(s)
}

__global__ __launch_bounds__(256) void topk_gate_dpp8(
    const float* __restrict__ w, float* __restrict__ out, int B)
{
    const int lane = threadIdx.x & 63;
    const int wv   = threadIdx.x >> 6;
    const int gw   = blockIdx.x * WAVES_PER_BLOCK + wv;
    const int gl   = lane & 7;           // position within the 8-lane row group

    for (int t = 0; t < ITER; ++t) {
        const int rowOct = gw * ITER + t;            // 8 rows per iteration
        if (rowOct * 8 >= B) return;                 // wave-uniform

        // lane l owns experts [8*(l&7), 8*(l&7)+8) of row rowOct*8 + (l>>3):
        // f32x4 indices 2l and 2l+1 within the wave's 2KB span.
        const size_t base = (size_t)rowOct * 128 + 2 * lane;
        const f32x4 va = reinterpret_cast<const f32x4*>(w)[base];
        const f32x4 vb = reinterpret_cast<const f32x4*>(w)[base + 1];
        float v[8] = { va.x, va.y, va.z, va.w, vb.x, vb.y, vb.z, vb.w };

        // per-lane descending sort-8
        float s[8];
        #pragma unroll
        for (int i = 0; i < 8; ++i) s[i] = v[i];
        SORT8_FULL(s)

        // top-8 across lane pairs (^1), quads (^2)
        merge8<DPP_QUAD_XOR1>(s);
        merge8<DPP_QUAD_XOR2>(s);

        // final merge across the two quads of the 8-group: multiset only
        float c[8];
        #pragma unroll
        for (int i = 0; i < 8; ++i) c[i] = fmaxf(s[i], dppf<DPP_HALF_MIR>(s[7 - i]));

        // thr = 8th largest = min of the top-8 multiset (valley-shaped c)
        float thr = fminf(fminf(fminf(c[0], c[1]), fminf(c[2], c[3])),
                          fminf(fminf(c[4], c[5]), fminf(c[6], c[7])));

        // strictly-greater count and L1 straight from the shared multiset
        int cgt = 0;
        #pragma unroll
        for (int i = 0; i < 8; ++i) cgt += (c[i] > thr) ? 1 : 0;
        const int budget = 8 - cgt;          // multiplicity of thr in top-8

        float l1 = 0.0f;
        #pragma unroll
        for (int i = 0; i < 8; ++i) l1 += fabsf(c[i]);
        const float scale = __builtin_amdgcn_rcpf(fmaxf(l1, L1_EPS));

        // equality census across the row
        int leq = 0;
        #pragma unroll
        for (int i = 0; i < 8; ++i) leq += (v[i] == thr) ? 1 : 0;
        int total_eq = leq;
        total_eq += dppi<DPP_QUAD_XOR1>(total_eq);
        total_eq += dppi<DPP_QUAD_XOR2>(total_eq);
        total_eq += dppi<DPP_HALF_MIR>(total_eq);

        bool take[8];
        if (__any(total_eq > budget)) {
            // cold: more ==thr than slots -> admit in expert-index order
            int pre = leq;
            #pragma unroll
            for (int d = 1; d < 8; d <<= 1) {
                const int u = __shfl_up(pre, d, 8);
                if (gl >= d) pre += u;
            }
            int eqb = pre - leq;             // equals at lower expert indices
            #pragma unroll
            for (int i = 0; i < 8; ++i) {
                const bool e = (v[i] == thr);
                take[i] = (v[i] > thr) || (e && eqb < budget);
                eqb += e ? 1 : 0;
            }
        } else {
            // total_eq == budget exactly -> every equal survives
            #pragma unroll
            for (int i = 0; i < 8; ++i) take[i] = v[i] >= thr;
        }

        f32x4 oa, ob;
        oa.x = take[0] ? v[0] * scale : 0.0f;
        oa.y = take[1] ? v[1] * scale : 0.0f;
        oa.z = take[2] ? v[2] * scale : 0.0f;
        oa.w = take[3] ? v[3] * scale : 0.0f;
        ob.x = take[4] ? v[4] * scale : 0.0f;
        ob.y = take[5] ? v[5] * scale : 0.0f;
        ob.z = take[6] ? v[6] * scale : 0.0f;
        ob.w = take[7] ? v[7] * scale : 0.0f;
        __builtin_nontemporal_store(oa, reinterpret_cast<f32x4*>(out) + base);
        __builtin_nontemporal_store(ob, reinterpret_cast<f32x4*>(out) + base + 1);
    }
}

extern "C" void kernel_launch(void* const* d_in, const int* in_sizes, int n_in,
                              void* d_out, int out_size, void* d_ws, size_t ws_size,
                              hipStream_t stream) {
    const float* w = (const float*)d_in[0];
    // d_in[1] is k (always 8 here; kernel is compile-time K=8).
    float* out = (float*)d_out;
    const int B = in_sizes[0] / E;

    const int rows_per_block = WAVES_PER_BLOCK * ITER * 8;   // 256
    const int grid = (B + rows_per_block - 1) / rows_per_block;
    topk_gate_dpp8<<<grid, 256, 0, stream>>>(w, out, B);
}